// Round 2
// baseline (309.935 us; speedup 1.0000x reference)
//
#include <hip/hip_runtime.h>
#include <math.h>

// Output: adj (M x M float32), M = N + 4 (N=8192 -> M=8196).
//   adj[i][i] = 1.0  for i < N
//   adj[i][j] = 0.25 for i,j >= N   (bottom-right 4x4 block, incl. diagonal)
//   else 0.
//
// Single fused kernel: one float4-store pass over the whole output.
// M = 8196 is divisible by 4 -> each row is exactly M/4 = 2049 float4 chunks,
// chunks never straddle rows, and the special 4x4 block (cols 8192..8195)
// is exactly the last chunk (index 2048) of rows N..M-1.
// The write of M*M*4 B = 262.4 MB is irreducible (d_out is re-poisoned to
// 0xAA before every timed launch), so the floor is ~42 us at 6.3 TB/s.

__global__ __launch_bounds__(256) void adj_fill_kernel(float4* __restrict__ out,
                                                       int N, int M4) {
    const int row = blockIdx.x;            // one block per row, M rows
    const size_t base = (size_t)row * (size_t)M4;

    if (row < N) {
        const int dc   = row >> 2;         // chunk containing the diagonal
        const int lane = row & 3;
        for (int c = threadIdx.x; c < M4; c += blockDim.x) {
            float4 v = make_float4(0.f, 0.f, 0.f, 0.f);
            if (c == dc) {
                ((float*)&v)[lane] = 1.0f; // diagonal: d_i * A * d_i = 1
            }
            out[base + c] = v;
        }
    } else {
        const int last = M4 - 1;           // chunk covering cols N..N+3
        for (int c = threadIdx.x; c < M4; c += blockDim.x) {
            float4 v = (c == last) ? make_float4(0.25f, 0.25f, 0.25f, 0.25f)
                                   : make_float4(0.f, 0.f, 0.f, 0.f);
            out[base + c] = v;
        }
    }
}

extern "C" void kernel_launch(void* const* d_in, const int* in_sizes, int n_in,
                              void* d_out, int out_size, void* d_ws, size_t ws_size,
                              hipStream_t stream) {
    (void)d_in; (void)in_sizes; (void)n_in; (void)d_ws; (void)ws_size;

    // M is the output's square dimension; derive from out_size (M*M elements).
    int M = (int)(sqrt((double)out_size) + 0.5);
    int N = M - 4;
    int M4 = M >> 2;                        // 2049 float4 chunks per row

    adj_fill_kernel<<<M, 256, 0, stream>>>((float4*)d_out, N, M4);
}

// Round 3
// 295.306 us; speedup vs baseline: 1.0495x; 1.0495x over previous
//
#include <hip/hip_runtime.h>
#include <math.h>

// Output: adj (M x M float32), M = N + 4 (N=8192 -> M=8196).
//   adj[i][i] = 1.0  for i < N
//   adj[i][j] = 0.25 for i,j >= N   (bottom-right 4x4 block, incl. diagonal)
//   else 0.
//
// Single fused kernel: one float4-store pass over the whole output.
// M = 8196 divisible by 4 -> each row is exactly M/4 = 2049 float4 chunks;
// chunks never straddle rows; the 4x4 block (cols 8192..8195) is exactly the
// last chunk of rows N..M-1.
//
// Round-2 lesson: ((float*)&v)[lane] = runtime-indexed local -> scratch
// demotion (rule #20), which tanked store BW. Build the vector with
// branch-free compares instead: v_cmp + v_cndmask, store stays dwordx4.

__global__ __launch_bounds__(256) void adj_fill_kernel(float4* __restrict__ out,
                                                       int N, int M4) {
    const int row = blockIdx.x;            // one block per row, M rows
    const size_t base = (size_t)row * (size_t)M4;

    if (row < N) {
        for (int c = threadIdx.x; c < M4; c += blockDim.x) {
            const int col = c << 2;
            float4 v;
            v.x = (col     == row) ? 1.0f : 0.0f;
            v.y = (col + 1 == row) ? 1.0f : 0.0f;
            v.z = (col + 2 == row) ? 1.0f : 0.0f;
            v.w = (col + 3 == row) ? 1.0f : 0.0f;
            out[base + c] = v;
        }
    } else {
        const int last = M4 - 1;           // chunk covering cols N..N+3
        for (int c = threadIdx.x; c < M4; c += blockDim.x) {
            const float s = (c == last) ? 0.25f : 0.0f;
            out[base + c] = make_float4(s, s, s, s);
        }
    }
}

extern "C" void kernel_launch(void* const* d_in, const int* in_sizes, int n_in,
                              void* d_out, int out_size, void* d_ws, size_t ws_size,
                              hipStream_t stream) {
    (void)d_in; (void)in_sizes; (void)n_in; (void)d_ws; (void)ws_size;

    // M is the output's square dimension; derive from out_size (M*M elements).
    int M = (int)(sqrt((double)out_size) + 0.5);
    int N = M - 4;
    int M4 = M >> 2;                        // float4 chunks per row (2049)

    adj_fill_kernel<<<M, 256, 0, stream>>>((float4*)d_out, N, M4);
}